// Round 17
// baseline (348.462 us; speedup 1.0000x reference)
//
#include <hip/hip_runtime.h>
#include <hip/hip_bf16.h>

// Fused attention forward: B=4, N=2048, C=1024, H=16, D=64.
// Round 17: BARRIER-FREE flash. Evidence: TLP-insensitive (R11~R14), dbuf null
// (R14), no pipe >50% -> barrier lockstep was the limiter. K/V per (b,h) is
// 512KB = L2-resident (guide m169: dropping LDS staging of L2-fit KV = +26%).
// Each wave loads K/V fragments per-lane global->VGPR (it consumes the whole
// tile anyway), zero LDS / zero barriers in the loop; waves free-run.
// Block = 256 thr = 4 waves x 32 q over full KV (no split-KV combine).
// qkv/proj rings + preps unchanged from round 16.

#define B_ 4
#define N_ 2048
#define C_ 1024
#define H_ 16
#define D_ 64
#define MCONST 24.0f
#define QSCALE (0.125f * 1.44269504088896340736f)

typedef __attribute__((ext_vector_type(8))) __bf16 bf16x8;
typedef __attribute__((ext_vector_type(4))) float f32x4;
typedef __attribute__((ext_vector_type(16))) float f32x16;
typedef unsigned int u32;
typedef __attribute__((ext_vector_type(2))) u32 u32x2;
typedef __attribute__((ext_vector_type(4))) u32 u32x4;

__device__ inline unsigned short f2bf(float f) {
  __bf16 h = (__bf16)f;
  return __builtin_bit_cast(unsigned short, h);
}

__device__ __forceinline__ u32 pk2(float lo, float hi) {
  return (u32)f2bf(lo) | ((u32)f2bf(hi) << 16);
}

__device__ __forceinline__ void gld16(const void* g, void* l) {
  __builtin_amdgcn_global_load_lds(
      (const __attribute__((address_space(1))) u32*)g,
      (__attribute__((address_space(3))) u32*)l, 16, 0, 0);
}

// ---- prep: fp32 -> bf16, same layout ----
__global__ __launch_bounds__(256) void cvt_bf16_kernel(
    const float* __restrict__ in, unsigned short* __restrict__ out) {
  int i = (blockIdx.x * 256 + threadIdx.x) * 8;
  float4 f0 = *(const float4*)&in[i];
  float4 f1 = *(const float4*)&in[i + 4];
  ushort4 h0, h1;
  h0.x = f2bf(f0.x); h0.y = f2bf(f0.y); h0.z = f2bf(f0.z); h0.w = f2bf(f0.w);
  h1.x = f2bf(f1.x); h1.y = f2bf(f1.y); h1.z = f2bf(f1.z); h1.w = f2bf(f1.w);
  *(ushort4*)&out[i] = h0;
  *(ushort4*)&out[i + 4] = h1;
}

// ---- prep: W[K][Nn] fp32 -> Wt[Nn][K] bf16 (32x32 tiles) ----
__global__ __launch_bounds__(256) void transpose_cvt_kernel(
    const float* __restrict__ in, unsigned short* __restrict__ out,
    int K, int Nn) {
  __shared__ float tile[32][33];
  const int t = threadIdx.x;
  const int k0 = blockIdx.y * 32, n0 = blockIdx.x * 32;
  {
    int r = t >> 3, c = (t & 7) * 4;
    float4 f = *(const float4*)&in[(size_t)(k0 + r) * Nn + n0 + c];
    tile[r][c + 0] = f.x; tile[r][c + 1] = f.y;
    tile[r][c + 2] = f.z; tile[r][c + 3] = f.w;
  }
  __syncthreads();
  {
    int nr = t >> 3, kc = (t & 7) * 4;
    ushort4 h;
    h.x = f2bf(tile[kc + 0][nr]);
    h.y = f2bf(tile[kc + 1][nr]);
    h.z = f2bf(tile[kc + 2][nr]);
    h.w = f2bf(tile[kc + 3][nr]);
    *(ushort4*)&out[(size_t)(n0 + nr) * K + k0 + kc] = h;
  }
}

// ---- 256^2 counted-vmcnt GEMM (qkv): C = A[M,K] @ Bt[Nout,K]^T ----
// Scatters bf16 to q(scaled)/k [B,H,N,D] and V TRANSPOSED to vtb [B,H,D,N].
__global__ __launch_bounds__(512, 1) void gemm256_kernel(
    const unsigned short* __restrict__ A, const unsigned short* __restrict__ Bt,
    unsigned short* __restrict__ qb, unsigned short* __restrict__ kb,
    unsigned short* __restrict__ vtb, int M, int K, int Nout)
{
  __shared__ unsigned short LDS[3][2][256 * 32];   // [buf][A|B] 96 KB
  const int tid = threadIdx.x;
  const int w = tid >> 6, lane = tid & 63;
  const int l15 = lane & 15, lk = lane >> 4;
  const int wm = w >> 2, wn = w & 3;               // 2 x 4 wave grid
  const int n0 = blockIdx.x * 256, m0 = blockIdx.y * 256;

  const int s_row = tid >> 2;
  const int s_col = ((tid & 3) * 8) ^ (((s_row >> 3) & 1) * 16);
  const int s_dst = tid * 8;
  const int kcol = (lk * 8) ^ (((l15 >> 3) & 1) * 16);

  f32x4 acc[8][4];
#pragma unroll
  for (int m = 0; m < 8; m++)
#pragma unroll
    for (int n = 0; n < 4; n++) acc[m][n] = f32x4{0.f, 0.f, 0.f, 0.f};

#pragma unroll
  for (int i = 0; i < 2; i++)
    gld16(&A[(size_t)(m0 + i * 128 + s_row) * K + s_col],
          &LDS[0][0][i * 4096 + s_dst]);
#pragma unroll
  for (int i = 0; i < 2; i++)
    gld16(&Bt[(size_t)(n0 + i * 128 + s_row) * K + s_col],
          &LDS[0][1][i * 4096 + s_dst]);

  int cur = 0;
  for (int j = 0; j < 31; ++j) {
    const int nxt = (cur + 1 == 3) ? 0 : cur + 1;
    const int kt = (j + 1) * 32;
#pragma unroll
    for (int i = 0; i < 2; i++)
      gld16(&A[(size_t)(m0 + i * 128 + s_row) * K + kt + s_col],
            &LDS[nxt][0][i * 4096 + s_dst]);
    asm volatile("s_waitcnt vmcnt(2)" ::: "memory");
    __builtin_amdgcn_s_barrier();
    asm volatile("" ::: "memory");

    bf16x8 bf[4], af[4];
#pragma unroll
    for (int n = 0; n < 4; n++)
      bf[n] = *(const bf16x8*)&LDS[cur][1][(wn * 64 + n * 16 + l15) * 32 + kcol];
#pragma unroll
    for (int m = 0; m < 4; m++)
      af[m] = *(const bf16x8*)&LDS[cur][0][(wm * 128 + m * 16 + l15) * 32 + kcol];
    __builtin_amdgcn_s_setprio(1);
#pragma unroll
    for (int m = 0; m < 4; m++)
#pragma unroll
      for (int n = 0; n < 4; n++)
        acc[m][n] = __builtin_amdgcn_mfma_f32_16x16x32_bf16(af[m], bf[n], acc[m][n], 0, 0, 0);
    __builtin_amdgcn_s_setprio(0);

#pragma unroll
    for (int i = 0; i < 2; i++)
      gld16(&Bt[(size_t)(n0 + i * 128 + s_row) * K + kt + s_col],
            &LDS[nxt][1][i * 4096 + s_dst]);

#pragma unroll
    for (int m = 0; m < 4; m++)
      af[m] = *(const bf16x8*)&LDS[cur][0][(wm * 128 + (m + 4) * 16 + l15) * 32 + kcol];
    __builtin_amdgcn_s_setprio(1);
#pragma unroll
    for (int m = 0; m < 4; m++)
#pragma unroll
      for (int n = 0; n < 4; n++)
        acc[m + 4][n] = __builtin_amdgcn_mfma_f32_16x16x32_bf16(af[m], bf[n], acc[m + 4][n], 0, 0, 0);
    __builtin_amdgcn_s_setprio(0);
    cur = nxt;
  }

  asm volatile("s_waitcnt vmcnt(0)" ::: "memory");
  __builtin_amdgcn_s_barrier();
  asm volatile("" ::: "memory");
  {
    bf16x8 bf[4], af[4];
#pragma unroll
    for (int n = 0; n < 4; n++)
      bf[n] = *(const bf16x8*)&LDS[cur][1][(wn * 64 + n * 16 + l15) * 32 + kcol];
#pragma unroll
    for (int m = 0; m < 4; m++)
      af[m] = *(const bf16x8*)&LDS[cur][0][(wm * 128 + m * 16 + l15) * 32 + kcol];
#pragma unroll
    for (int m = 0; m < 4; m++)
#pragma unroll
      for (int n = 0; n < 4; n++)
        acc[m][n] = __builtin_amdgcn_mfma_f32_16x16x32_bf16(af[m], bf[n], acc[m][n], 0, 0, 0);
#pragma unroll
    for (int m = 0; m < 4; m++)
      af[m] = *(const bf16x8*)&LDS[cur][0][(wm * 128 + (m + 4) * 16 + l15) * 32 + kcol];
#pragma unroll
    for (int m = 0; m < 4; m++)
#pragma unroll
      for (int n = 0; n < 4; n++)
        acc[m + 4][n] = __builtin_amdgcn_mfma_f32_16x16x32_bf16(af[m], bf[n], acc[m + 4][n], 0, 0, 0);
  }

  // epilogue: q/k scatter [B,H,N,D]; V written TRANSPOSED [B,H,D,N].
#pragma unroll
  for (int n = 0; n < 4; n++) {
    int c = n0 + wn * 64 + n * 16 + l15;
    int tsel = c >> 10, h = (c >> 6) & 15, d = c & 63;
    if (tsel < 2) {
      unsigned short* dst = (tsel == 0) ? qb : kb;
      float sc = (tsel == 0) ? QSCALE : 1.0f;
#pragma unroll
      for (int m = 0; m < 8; m++) {
#pragma unroll
        for (int r = 0; r < 4; r++) {
          int row = m0 + wm * 128 + m * 16 + lk * 4 + r;
          int b = row >> 11, nn = row & 2047;
          dst[(((size_t)(b * 16 + h)) * 2048 + nn) * 64 + d] = f2bf(acc[m][n][r] * sc);
        }
      }
    } else {
#pragma unroll
      for (int m = 0; m < 8; m++) {
        int row0 = m0 + wm * 128 + m * 16 + lk * 4;      // 4-aligned
        int b = row0 >> 11, nn = row0 & 2047;
        ushort4 pv;
        pv.x = f2bf(acc[m][n][0]); pv.y = f2bf(acc[m][n][1]);
        pv.z = f2bf(acc[m][n][2]); pv.w = f2bf(acc[m][n][3]);
        *(ushort4*)&vtb[(((size_t)(b * 16 + h)) * 64 + d) * 2048 + nn] = pv;
      }
    }
  }
}

// ---- 256x128-tile counted-vmcnt GEMM (proj): out = A @ Bt^T + bias ----
__global__ __launch_bounds__(512, 1) void gemmproj_kernel(
    const unsigned short* __restrict__ A, const unsigned short* __restrict__ Bt,
    const float* __restrict__ bias, float* __restrict__ outp,
    int M, int K, int Nout)
{
  __shared__ unsigned short LDS[3][12288];   // [buf][A 8192 | B 4096] 72 KB
  const int tid = threadIdx.x;
  const int w = tid >> 6, lane = tid & 63;
  const int l15 = lane & 15, lk = lane >> 4;
  const int wm = w >> 1, wn = w & 1;         // 4 x 2 wave grid
  const int n0 = blockIdx.x * 128, m0 = blockIdx.y * 256;

  const int s_row = tid >> 2;
  const int s_col = ((tid & 3) * 8) ^ (((s_row >> 3) & 1) * 16);
  const int s_dst = tid * 8;
  const int kcol = (lk * 8) ^ (((l15 >> 3) & 1) * 16);

  f32x4 acc[4][4];
#pragma unroll
  for (int m = 0; m < 4; m++)
#pragma unroll
    for (int n = 0; n < 4; n++) acc[m][n] = f32x4{0.f, 0.f, 0.f, 0.f};

#pragma unroll
  for (int i = 0; i < 2; i++)
    gld16(&A[(size_t)(m0 + i * 128 + s_row) * K + s_col],
          &LDS[0][i * 4096 + s_dst]);
  gld16(&Bt[(size_t)(n0 + s_row) * K + s_col], &LDS[0][8192 + s_dst]);

  int cur = 0;
  for (int j = 0; j < 31; ++j) {
    const int nxt = (cur + 1 == 3) ? 0 : cur + 1;
    const int kt = (j + 1) * 32;
#pragma unroll
    for (int i = 0; i < 2; i++)
      gld16(&A[(size_t)(m0 + i * 128 + s_row) * K + kt + s_col],
            &LDS[nxt][i * 4096 + s_dst]);
    asm volatile("s_waitcnt vmcnt(2)" ::: "memory");
    __builtin_amdgcn_s_barrier();
    asm volatile("" ::: "memory");

    bf16x8 bf[4], af[2];
#pragma unroll
    for (int n = 0; n < 4; n++)
      bf[n] = *(const bf16x8*)&LDS[cur][8192 + (wn * 64 + n * 16 + l15) * 32 + kcol];
#pragma unroll
    for (int m = 0; m < 2; m++)
      af[m] = *(const bf16x8*)&LDS[cur][(wm * 64 + m * 16 + l15) * 32 + kcol];
    __builtin_amdgcn_s_setprio(1);
#pragma unroll
    for (int m = 0; m < 2; m++)
#pragma unroll
      for (int n = 0; n < 4; n++)
        acc[m][n] = __builtin_amdgcn_mfma_f32_16x16x32_bf16(af[m], bf[n], acc[m][n], 0, 0, 0);
    __builtin_amdgcn_s_setprio(0);

    gld16(&Bt[(size_t)(n0 + s_row) * K + kt + s_col], &LDS[nxt][8192 + s_dst]);

#pragma unroll
    for (int m = 0; m < 2; m++)
      af[m] = *(const bf16x8*)&LDS[cur][(wm * 64 + (m + 2) * 16 + l15) * 32 + kcol];
    __builtin_amdgcn_s_setprio(1);
#pragma unroll
    for (int m = 0; m < 2; m++)
#pragma unroll
      for (int n = 0; n < 4; n++)
        acc[m + 2][n] = __builtin_amdgcn_mfma_f32_16x16x32_bf16(af[m], bf[n], acc[m + 2][n], 0, 0, 0);
    __builtin_amdgcn_s_setprio(0);
    cur = nxt;
  }

  asm volatile("s_waitcnt vmcnt(0)" ::: "memory");
  __builtin_amdgcn_s_barrier();
  asm volatile("" ::: "memory");
  {
    bf16x8 bf[4], af[2];
#pragma unroll
    for (int n = 0; n < 4; n++)
      bf[n] = *(const bf16x8*)&LDS[cur][8192 + (wn * 64 + n * 16 + l15) * 32 + kcol];
#pragma unroll
    for (int m = 0; m < 2; m++)
      af[m] = *(const bf16x8*)&LDS[cur][(wm * 64 + m * 16 + l15) * 32 + kcol];
#pragma unroll
    for (int m = 0; m < 2; m++)
#pragma unroll
      for (int n = 0; n < 4; n++)
        acc[m][n] = __builtin_amdgcn_mfma_f32_16x16x32_bf16(af[m], bf[n], acc[m][n], 0, 0, 0);
#pragma unroll
    for (int m = 0; m < 2; m++)
      af[m] = *(const bf16x8*)&LDS[cur][(wm * 64 + (m + 2) * 16 + l15) * 32 + kcol];
#pragma unroll
    for (int m = 0; m < 2; m++)
#pragma unroll
      for (int n = 0; n < 4; n++)
        acc[m + 2][n] = __builtin_amdgcn_mfma_f32_16x16x32_bf16(af[m], bf[n], acc[m + 2][n], 0, 0, 0);
  }

#pragma unroll
  for (int n = 0; n < 4; n++) {
    int c = n0 + wn * 64 + n * 16 + l15;
    float bv = bias[c];
#pragma unroll
    for (int m = 0; m < 4; m++) {
#pragma unroll
      for (int r = 0; r < 4; r++) {
        int row = m0 + wm * 64 + m * 16 + lk * 4 + r;
        outp[(size_t)row * Nout + c] = acc[m][n][r] + bv;
      }
    }
  }
}

// ---- Flash attention: barrier-free, 256 thr = 4 waves x 32 q, full KV. ----
// K frags direct from kb [bh][n][d]; V frags direct from vtb [bh][d][n].
// Swapped QK^T (A=K, B=Q regs), in-register P, static-max softmax.
__global__ __launch_bounds__(256) void flash_kernel(
    const unsigned short* __restrict__ qb, const unsigned short* __restrict__ kb,
    const unsigned short* __restrict__ vtb, unsigned short* __restrict__ ob)
{
  __shared__ float Lw[4][32];              // per-wave row-sum broadcast (512 B)
  const int tid = threadIdx.x;
  const int w = tid >> 6;
  const int lane = tid & 63;
  const int l31 = lane & 31;
  const int hi = lane >> 5;
  const int q0 = blockIdx.x * 128;
  const int bh = blockIdx.y;
  const size_t base = (size_t)bh * N_ * D_;
  const unsigned short* Qg = qb + base;
  const unsigned short* Kg = kb + base;
  const unsigned short* Vtg = vtb + base;  // [d][n]

  // Q fragments (B-operand): lane -> q = w*32+l31, k = ds*16+hi*8+j
  const int qrow_g = q0 + w * 32 + l31;
  bf16x8 qf[4];
#pragma unroll
  for (int ds = 0; ds < 4; ds++)
    qf[ds] = *(const bf16x8*)&Qg[(size_t)qrow_g * 64 + ds * 16 + hi * 8];

  f32x16 acc0, acc1, minit;
#pragma unroll
  for (int i = 0; i < 16; i++) { acc0[i] = 0.f; acc1[i] = 0.f; minit[i] = -MCONST; }
  float lrow = 0.f;

  for (int kv0 = 0; kv0 < N_; kv0 += 64) {
    // K frags (A-operand): lane -> kv = t*32+l31, d = ds*16+hi*8+j  (16B/lane)
    bf16x8 kf[2][4];
#pragma unroll
    for (int t = 0; t < 2; t++)
#pragma unroll
      for (int ds = 0; ds < 4; ds++)
        kf[t][ds] = *(const bf16x8*)&Kg[(size_t)(kv0 + t * 32 + l31) * 64 + ds * 16 + hi * 8];

    // V frags (B-operand): lane -> d = dt*32+l31, kv = ks*16+hi*8+j (16B/lane)
    bf16x8 vf[2][4];
#pragma unroll
    for (int dt = 0; dt < 2; dt++)
#pragma unroll
      for (int ks = 0; ks < 4; ks++)
        vf[dt][ks] = *(const bf16x8*)&Vtg[(size_t)(dt * 32 + l31) * N_ + kv0 + ks * 16 + hi * 8];

    // S^T tiles: C-init -24 = static max shift
    f32x16 sa0 = minit, sa1 = minit;
    __builtin_amdgcn_s_setprio(1);
#pragma unroll
    for (int ds = 0; ds < 4; ds++)
      sa0 = __builtin_amdgcn_mfma_f32_32x32x16_bf16(kf[0][ds], qf[ds], sa0, 0, 0, 0);
#pragma unroll
    for (int ds = 0; ds < 4; ds++)
      sa1 = __builtin_amdgcn_mfma_f32_32x32x16_bf16(kf[1][ds], qf[ds], sa1, 0, 0, 0);
    __builtin_amdgcn_s_setprio(0);

    u32 F[4][4];
#pragma unroll
    for (int t = 0; t < 2; t++) {
      const f32x16& sa = t ? sa1 : sa0;
      float p[16];
#pragma unroll
      for (int r = 0; r < 16; r++) p[r] = __builtin_amdgcn_exp2f(sa[r]);
      lrow += ((p[0] + p[1]) + (p[2] + p[3])) + ((p[4] + p[5]) + (p[6] + p[7]))
            + ((p[8] + p[9]) + (p[10] + p[11])) + ((p[12] + p[13]) + (p[14] + p[15]));

      u32 pk[8];
#pragma unroll
      for (int j = 0; j < 8; j++) pk[j] = pk2(p[2 * j], p[2 * j + 1]);
#if __has_builtin(__builtin_amdgcn_permlane32_swap)
      u32x2 r02 = __builtin_amdgcn_permlane32_swap(pk[0], pk[2], false, false);
      u32x2 r13 = __builtin_amdgcn_permlane32_swap(pk[1], pk[3], false, false);
      u32x2 r46 = __builtin_amdgcn_permlane32_swap(pk[4], pk[6], false, false);
      u32x2 r57 = __builtin_amdgcn_permlane32_swap(pk[5], pk[7], false, false);
      F[2 * t][0] = r02[0]; F[2 * t][2] = r02[1];
      F[2 * t][1] = r13[0]; F[2 * t][3] = r13[1];
      F[2 * t + 1][0] = r46[0]; F[2 * t + 1][2] = r46[1];
      F[2 * t + 1][1] = r57[0]; F[2 * t + 1][3] = r57[1];
#else
      u32 sw[8];
#pragma unroll
      for (int j = 0; j < 8; j++) sw[j] = (u32)__shfl_xor((int)pk[j], 32);
      F[2 * t][0] = hi ? sw[2] : pk[0];
      F[2 * t][1] = hi ? sw[3] : pk[1];
      F[2 * t][2] = hi ? pk[2] : sw[0];
      F[2 * t][3] = hi ? pk[3] : sw[1];
      F[2 * t + 1][0] = hi ? sw[6] : pk[4];
      F[2 * t + 1][1] = hi ? sw[7] : pk[5];
      F[2 * t + 1][2] = hi ? pk[6] : sw[4];
      F[2 * t + 1][3] = hi ? pk[7] : sw[5];
#endif
    }

    // O += P V : A = P frags (regs), B = V frags (regs)
    __builtin_amdgcn_s_setprio(1);
#pragma unroll
    for (int ks = 0; ks < 4; ks++) {
      u32x4 fv = {F[ks][0], F[ks][1], F[ks][2], F[ks][3]};
      bf16x8 a = __builtin_bit_cast(bf16x8, fv);
      acc0 = __builtin_amdgcn_mfma_f32_32x32x16_bf16(a, vf[0][ks], acc0, 0, 0, 0);
      acc1 = __builtin_amdgcn_mfma_f32_32x32x16_bf16(a, vf[1][ks], acc1, 0, 0, 0);
    }
    __builtin_amdgcn_s_setprio(0);
  }

  // row sums: lane pair (l, l+32) holds complementary kv-slot partials
  float rs = lrow + __shfl_xor(lrow, 32);
  if (lane < 32) Lw[w][l31] = rs;          // intra-wave write->read: no barrier

  const int b = bh >> 4, h = bh & 15;
#pragma unroll
  for (int r = 0; r < 16; r++) {
    int qr = (r & 3) + 8 * (r >> 2) + 4 * hi;
    float inv = 1.0f / Lw[w][qr];
    int nq = q0 + w * 32 + qr;
    size_t ob0 = (((size_t)b * N_ + nq) * H_ + h) * D_;
    ob[ob0 + l31]      = f2bf(acc0[r] * inv);
    ob[ob0 + 32 + l31] = f2bf(acc1[r] * inv);
  }
}

extern "C" void kernel_launch(void* const* d_in, const int* in_sizes, int n_in,
                              void* d_out, int out_size, void* d_ws, size_t ws_size,
                              hipStream_t stream) {
  const float* x      = (const float*)d_in[0];
  const float* w_qkv  = (const float*)d_in[1];
  const float* w_proj = (const float*)d_in[2];
  const float* b_proj = (const float*)d_in[3];
  float* out = (float*)d_out;

  const size_t qsz = (size_t)B_ * H_ * N_ * D_;
  unsigned short* qb     = (unsigned short*)d_ws;
  unsigned short* kb     = qb + qsz;
  unsigned short* vtb    = kb + qsz;                      // V transposed [bh][d][n]
  unsigned short* xbf    = vtb + qsz;
  unsigned short* ob     = xbf;                           // alias: x dead after qkv
  unsigned short* wqkv_t = xbf + qsz;
  unsigned short* wproj_t= wqkv_t + (size_t)3072 * 1024;

  cvt_bf16_kernel<<<4096, 256, 0, stream>>>(x, xbf);
  transpose_cvt_kernel<<<dim3(3072 / 32, 1024 / 32), 256, 0, stream>>>(w_qkv, wqkv_t, 1024, 3072);
  transpose_cvt_kernel<<<dim3(1024 / 32, 1024 / 32), 256, 0, stream>>>(w_proj, wproj_t, 1024, 1024);

  gemm256_kernel<<<dim3(3072 / 256, 8192 / 256), 512, 0, stream>>>(
      xbf, wqkv_t, qb, kb, vtb, 8192, 1024, 3072);

  flash_kernel<<<dim3(N_ / 128, B_ * H_), 256, 0, stream>>>(qb, kb, vtb, ob);

  gemmproj_kernel<<<dim3(1024 / 128, 8192 / 256), 512, 0, stream>>>(
      ob, wproj_t, b_proj, out, 8192, 1024, 1024);
}

// Round 18
// 210.375 us; speedup vs baseline: 1.6564x; 1.6564x over previous
//
#include <hip/hip_runtime.h>
#include <hip/hip_bf16.h>

// Fused attention forward: B=4, N=2048, C=1024, H=16, D=64.
// Round 18: REVERT flash to R14/R16 staged split-KV dbuf structure (R17's
// barrier-free direct-global was -2.4x: per-wave L2 latency serialization).
// Single rider: grid swap (bh on x, qtile on y) -> all 16 blocks sharing one
// bh's KV land on ONE XCD (id = qt*64+bh, xcd = id%8 = bh%8); 8 bh x 512KB
// = 4MB = one L2. Was: KV replicated across all 8 XCDs (FETCH 2.8x ideal).
// qkv/proj rings + preps unchanged from round 16.

#define B_ 4
#define N_ 2048
#define C_ 1024
#define H_ 16
#define D_ 64
#define MCONST 24.0f
#define QSCALE (0.125f * 1.44269504088896340736f)

typedef __attribute__((ext_vector_type(8))) __bf16 bf16x8;
typedef __attribute__((ext_vector_type(4))) float f32x4;
typedef __attribute__((ext_vector_type(16))) float f32x16;
typedef unsigned int u32;
typedef __attribute__((ext_vector_type(2))) u32 u32x2;
typedef __attribute__((ext_vector_type(4))) u32 u32x4;

__device__ inline unsigned short f2bf(float f) {
  __bf16 h = (__bf16)f;
  return __builtin_bit_cast(unsigned short, h);
}

__device__ __forceinline__ u32 pk2(float lo, float hi) {
  return (u32)f2bf(lo) | ((u32)f2bf(hi) << 16);
}

__device__ __forceinline__ void gld16(const void* g, void* l) {
  __builtin_amdgcn_global_load_lds(
      (const __attribute__((address_space(1))) u32*)g,
      (__attribute__((address_space(3))) u32*)l, 16, 0, 0);
}

// ---- prep: fp32 -> bf16, same layout ----
__global__ __launch_bounds__(256) void cvt_bf16_kernel(
    const float* __restrict__ in, unsigned short* __restrict__ out) {
  int i = (blockIdx.x * 256 + threadIdx.x) * 8;
  float4 f0 = *(const float4*)&in[i];
  float4 f1 = *(const float4*)&in[i + 4];
  ushort4 h0, h1;
  h0.x = f2bf(f0.x); h0.y = f2bf(f0.y); h0.z = f2bf(f0.z); h0.w = f2bf(f0.w);
  h1.x = f2bf(f1.x); h1.y = f2bf(f1.y); h1.z = f2bf(f1.z); h1.w = f2bf(f1.w);
  *(ushort4*)&out[i] = h0;
  *(ushort4*)&out[i + 4] = h1;
}

// ---- prep: W[K][Nn] fp32 -> Wt[Nn][K] bf16 (32x32 tiles) ----
__global__ __launch_bounds__(256) void transpose_cvt_kernel(
    const float* __restrict__ in, unsigned short* __restrict__ out,
    int K, int Nn) {
  __shared__ float tile[32][33];
  const int t = threadIdx.x;
  const int k0 = blockIdx.y * 32, n0 = blockIdx.x * 32;
  {
    int r = t >> 3, c = (t & 7) * 4;
    float4 f = *(const float4*)&in[(size_t)(k0 + r) * Nn + n0 + c];
    tile[r][c + 0] = f.x; tile[r][c + 1] = f.y;
    tile[r][c + 2] = f.z; tile[r][c + 3] = f.w;
  }
  __syncthreads();
  {
    int nr = t >> 3, kc = (t & 7) * 4;
    ushort4 h;
    h.x = f2bf(tile[kc + 0][nr]);
    h.y = f2bf(tile[kc + 1][nr]);
    h.z = f2bf(tile[kc + 2][nr]);
    h.w = f2bf(tile[kc + 3][nr]);
    *(ushort4*)&out[(size_t)(n0 + nr) * K + k0 + kc] = h;
  }
}

// ---- 256^2 counted-vmcnt GEMM (qkv): C = A[M,K] @ Bt[Nout,K]^T ----
// Scatters bf16 to q(scaled)/k [B,H,N,D] and V TRANSPOSED to vtb [B,H,D,N].
__global__ __launch_bounds__(512, 1) void gemm256_kernel(
    const unsigned short* __restrict__ A, const unsigned short* __restrict__ Bt,
    unsigned short* __restrict__ qb, unsigned short* __restrict__ kb,
    unsigned short* __restrict__ vtb, int M, int K, int Nout)
{
  __shared__ unsigned short LDS[3][2][256 * 32];   // [buf][A|B] 96 KB
  const int tid = threadIdx.x;
  const int w = tid >> 6, lane = tid & 63;
  const int l15 = lane & 15, lk = lane >> 4;
  const int wm = w >> 2, wn = w & 3;               // 2 x 4 wave grid
  const int n0 = blockIdx.x * 256, m0 = blockIdx.y * 256;

  const int s_row = tid >> 2;
  const int s_col = ((tid & 3) * 8) ^ (((s_row >> 3) & 1) * 16);
  const int s_dst = tid * 8;
  const int kcol = (lk * 8) ^ (((l15 >> 3) & 1) * 16);

  f32x4 acc[8][4];
#pragma unroll
  for (int m = 0; m < 8; m++)
#pragma unroll
    for (int n = 0; n < 4; n++) acc[m][n] = f32x4{0.f, 0.f, 0.f, 0.f};

#pragma unroll
  for (int i = 0; i < 2; i++)
    gld16(&A[(size_t)(m0 + i * 128 + s_row) * K + s_col],
          &LDS[0][0][i * 4096 + s_dst]);
#pragma unroll
  for (int i = 0; i < 2; i++)
    gld16(&Bt[(size_t)(n0 + i * 128 + s_row) * K + s_col],
          &LDS[0][1][i * 4096 + s_dst]);

  int cur = 0;
  for (int j = 0; j < 31; ++j) {
    const int nxt = (cur + 1 == 3) ? 0 : cur + 1;
    const int kt = (j + 1) * 32;
#pragma unroll
    for (int i = 0; i < 2; i++)
      gld16(&A[(size_t)(m0 + i * 128 + s_row) * K + kt + s_col],
            &LDS[nxt][0][i * 4096 + s_dst]);
    asm volatile("s_waitcnt vmcnt(2)" ::: "memory");
    __builtin_amdgcn_s_barrier();
    asm volatile("" ::: "memory");

    bf16x8 bf[4], af[4];
#pragma unroll
    for (int n = 0; n < 4; n++)
      bf[n] = *(const bf16x8*)&LDS[cur][1][(wn * 64 + n * 16 + l15) * 32 + kcol];
#pragma unroll
    for (int m = 0; m < 4; m++)
      af[m] = *(const bf16x8*)&LDS[cur][0][(wm * 128 + m * 16 + l15) * 32 + kcol];
    __builtin_amdgcn_s_setprio(1);
#pragma unroll
    for (int m = 0; m < 4; m++)
#pragma unroll
      for (int n = 0; n < 4; n++)
        acc[m][n] = __builtin_amdgcn_mfma_f32_16x16x32_bf16(af[m], bf[n], acc[m][n], 0, 0, 0);
    __builtin_amdgcn_s_setprio(0);

#pragma unroll
    for (int i = 0; i < 2; i++)
      gld16(&Bt[(size_t)(n0 + i * 128 + s_row) * K + kt + s_col],
            &LDS[nxt][1][i * 4096 + s_dst]);

#pragma unroll
    for (int m = 0; m < 4; m++)
      af[m] = *(const bf16x8*)&LDS[cur][0][(wm * 128 + (m + 4) * 16 + l15) * 32 + kcol];
    __builtin_amdgcn_s_setprio(1);
#pragma unroll
    for (int m = 0; m < 4; m++)
#pragma unroll
      for (int n = 0; n < 4; n++)
        acc[m + 4][n] = __builtin_amdgcn_mfma_f32_16x16x32_bf16(af[m], bf[n], acc[m + 4][n], 0, 0, 0);
    __builtin_amdgcn_s_setprio(0);
    cur = nxt;
  }

  asm volatile("s_waitcnt vmcnt(0)" ::: "memory");
  __builtin_amdgcn_s_barrier();
  asm volatile("" ::: "memory");
  {
    bf16x8 bf[4], af[4];
#pragma unroll
    for (int n = 0; n < 4; n++)
      bf[n] = *(const bf16x8*)&LDS[cur][1][(wn * 64 + n * 16 + l15) * 32 + kcol];
#pragma unroll
    for (int m = 0; m < 4; m++)
      af[m] = *(const bf16x8*)&LDS[cur][0][(wm * 128 + m * 16 + l15) * 32 + kcol];
#pragma unroll
    for (int m = 0; m < 4; m++)
#pragma unroll
      for (int n = 0; n < 4; n++)
        acc[m][n] = __builtin_amdgcn_mfma_f32_16x16x32_bf16(af[m], bf[n], acc[m][n], 0, 0, 0);
#pragma unroll
    for (int m = 0; m < 4; m++)
      af[m] = *(const bf16x8*)&LDS[cur][0][(wm * 128 + (m + 4) * 16 + l15) * 32 + kcol];
#pragma unroll
    for (int m = 0; m < 4; m++)
#pragma unroll
      for (int n = 0; n < 4; n++)
        acc[m + 4][n] = __builtin_amdgcn_mfma_f32_16x16x32_bf16(af[m], bf[n], acc[m + 4][n], 0, 0, 0);
  }

#pragma unroll
  for (int n = 0; n < 4; n++) {
    int c = n0 + wn * 64 + n * 16 + l15;
    int tsel = c >> 10, h = (c >> 6) & 15, d = c & 63;
    if (tsel < 2) {
      unsigned short* dst = (tsel == 0) ? qb : kb;
      float sc = (tsel == 0) ? QSCALE : 1.0f;
#pragma unroll
      for (int m = 0; m < 8; m++) {
#pragma unroll
        for (int r = 0; r < 4; r++) {
          int row = m0 + wm * 128 + m * 16 + lk * 4 + r;
          int b = row >> 11, nn = row & 2047;
          dst[(((size_t)(b * 16 + h)) * 2048 + nn) * 64 + d] = f2bf(acc[m][n][r] * sc);
        }
      }
    } else {
#pragma unroll
      for (int m = 0; m < 8; m++) {
        int row0 = m0 + wm * 128 + m * 16 + lk * 4;      // 4-aligned
        int b = row0 >> 11, nn = row0 & 2047;
        ushort4 pv;
        pv.x = f2bf(acc[m][n][0]); pv.y = f2bf(acc[m][n][1]);
        pv.z = f2bf(acc[m][n][2]); pv.w = f2bf(acc[m][n][3]);
        *(ushort4*)&vtb[(((size_t)(b * 16 + h)) * 64 + d) * 2048 + nn] = pv;
      }
    }
  }
}

// ---- 256x128-tile counted-vmcnt GEMM (proj): out = A @ Bt^T + bias ----
__global__ __launch_bounds__(512, 1) void gemmproj_kernel(
    const unsigned short* __restrict__ A, const unsigned short* __restrict__ Bt,
    const float* __restrict__ bias, float* __restrict__ outp,
    int M, int K, int Nout)
{
  __shared__ unsigned short LDS[3][12288];   // [buf][A 8192 | B 4096] 72 KB
  const int tid = threadIdx.x;
  const int w = tid >> 6, lane = tid & 63;
  const int l15 = lane & 15, lk = lane >> 4;
  const int wm = w >> 1, wn = w & 1;         // 4 x 2 wave grid
  const int n0 = blockIdx.x * 128, m0 = blockIdx.y * 256;

  const int s_row = tid >> 2;
  const int s_col = ((tid & 3) * 8) ^ (((s_row >> 3) & 1) * 16);
  const int s_dst = tid * 8;
  const int kcol = (lk * 8) ^ (((l15 >> 3) & 1) * 16);

  f32x4 acc[4][4];
#pragma unroll
  for (int m = 0; m < 4; m++)
#pragma unroll
    for (int n = 0; n < 4; n++) acc[m][n] = f32x4{0.f, 0.f, 0.f, 0.f};

#pragma unroll
  for (int i = 0; i < 2; i++)
    gld16(&A[(size_t)(m0 + i * 128 + s_row) * K + s_col],
          &LDS[0][i * 4096 + s_dst]);
  gld16(&Bt[(size_t)(n0 + s_row) * K + s_col], &LDS[0][8192 + s_dst]);

  int cur = 0;
  for (int j = 0; j < 31; ++j) {
    const int nxt = (cur + 1 == 3) ? 0 : cur + 1;
    const int kt = (j + 1) * 32;
#pragma unroll
    for (int i = 0; i < 2; i++)
      gld16(&A[(size_t)(m0 + i * 128 + s_row) * K + kt + s_col],
            &LDS[nxt][i * 4096 + s_dst]);
    asm volatile("s_waitcnt vmcnt(2)" ::: "memory");
    __builtin_amdgcn_s_barrier();
    asm volatile("" ::: "memory");

    bf16x8 bf[4], af[2];
#pragma unroll
    for (int n = 0; n < 4; n++)
      bf[n] = *(const bf16x8*)&LDS[cur][8192 + (wn * 64 + n * 16 + l15) * 32 + kcol];
#pragma unroll
    for (int m = 0; m < 2; m++)
      af[m] = *(const bf16x8*)&LDS[cur][(wm * 64 + m * 16 + l15) * 32 + kcol];
    __builtin_amdgcn_s_setprio(1);
#pragma unroll
    for (int m = 0; m < 2; m++)
#pragma unroll
      for (int n = 0; n < 4; n++)
        acc[m][n] = __builtin_amdgcn_mfma_f32_16x16x32_bf16(af[m], bf[n], acc[m][n], 0, 0, 0);
    __builtin_amdgcn_s_setprio(0);

    gld16(&Bt[(size_t)(n0 + s_row) * K + kt + s_col], &LDS[nxt][8192 + s_dst]);

#pragma unroll
    for (int m = 0; m < 2; m++)
      af[m] = *(const bf16x8*)&LDS[cur][(wm * 64 + (m + 2) * 16 + l15) * 32 + kcol];
    __builtin_amdgcn_s_setprio(1);
#pragma unroll
    for (int m = 0; m < 2; m++)
#pragma unroll
      for (int n = 0; n < 4; n++)
        acc[m + 2][n] = __builtin_amdgcn_mfma_f32_16x16x32_bf16(af[m], bf[n], acc[m + 2][n], 0, 0, 0);
    __builtin_amdgcn_s_setprio(0);
    cur = nxt;
  }

  asm volatile("s_waitcnt vmcnt(0)" ::: "memory");
  __builtin_amdgcn_s_barrier();
  asm volatile("" ::: "memory");
  {
    bf16x8 bf[4], af[2];
#pragma unroll
    for (int n = 0; n < 4; n++)
      bf[n] = *(const bf16x8*)&LDS[cur][8192 + (wn * 64 + n * 16 + l15) * 32 + kcol];
#pragma unroll
    for (int m = 0; m < 2; m++)
      af[m] = *(const bf16x8*)&LDS[cur][(wm * 64 + m * 16 + l15) * 32 + kcol];
#pragma unroll
    for (int m = 0; m < 2; m++)
#pragma unroll
      for (int n = 0; n < 4; n++)
        acc[m][n] = __builtin_amdgcn_mfma_f32_16x16x32_bf16(af[m], bf[n], acc[m][n], 0, 0, 0);
#pragma unroll
    for (int m = 0; m < 2; m++)
      af[m] = *(const bf16x8*)&LDS[cur][(wm * 64 + (m + 2) * 16 + l15) * 32 + kcol];
#pragma unroll
    for (int m = 0; m < 2; m++)
#pragma unroll
      for (int n = 0; n < 4; n++)
        acc[m + 2][n] = __builtin_amdgcn_mfma_f32_16x16x32_bf16(af[m], bf[n], acc[m + 2][n], 0, 0, 0);
  }

#pragma unroll
  for (int n = 0; n < 4; n++) {
    int c = n0 + wn * 64 + n * 16 + l15;
    float bv = bias[c];
#pragma unroll
    for (int m = 0; m < 4; m++) {
#pragma unroll
      for (int r = 0; r < 4; r++) {
        int row = m0 + wm * 64 + m * 16 + lk * 4 + r;
        outp[(size_t)row * Nout + c] = acc[m][n][r] + bv;
      }
    }
  }
}

// ---- Flash attention: R14 structure; grid = (bh, qtile) for KV locality. ----
// 512 threads = 2 groups x 4 waves; group g does KV half, double-buffered.
// Swapped QK^T (A=K, B=Q regs), in-register P, static-max softmax.
__global__ __launch_bounds__(512) void flash_kernel(
    const unsigned short* __restrict__ qb, const unsigned short* __restrict__ kb,
    const unsigned short* __restrict__ vtb, unsigned short* __restrict__ ob)
{
  __shared__ unsigned short KVs[2][2][2][64 * 64]; // [group][buf][K/V] 64 KB
  __shared__ float Lf[2][128];
  float* scratch = (float*)&KVs[0][0][0][0];

  const int tid = threadIdx.x;
  const int w = tid >> 6;
  const int lane = tid & 63;
  const int l31 = lane & 31;
  const int hi = lane >> 5;
  const int g = w >> 2;
  const int ws = w & 3;
  const int bh = blockIdx.x;               // x = bh: same-bh blocks share XCD
  const int q0 = blockIdx.y * 128;
  const size_t base = (size_t)bh * N_ * D_;
  const unsigned short* Qg = qb + base;
  const unsigned short* Kg = kb + base;
  const unsigned short* Vtg = vtb + base;

  const int t8 = tid & 255;
  const int s_r = t8 >> 3;
  const int s_sl = (t8 & 7) ^ (s_r & 7);
  const int swz = (lane & 7) << 3;

  const int qrow_g = q0 + ws * 32 + l31;
  bf16x8 qf[4];
#pragma unroll
  for (int ds = 0; ds < 4; ds++)
    qf[ds] = *(const bf16x8*)&Qg[(size_t)qrow_g * 64 + ds * 16 + hi * 8];

  f32x16 acc0, acc1, minit;
#pragma unroll
  for (int i = 0; i < 16; i++) { acc0[i] = 0.f; acc1[i] = 0.f; minit[i] = -MCONST; }
  float lrow = 0.f;

  const int kvbeg = g * (N_ / 2);

#pragma unroll
  for (int i = 0; i < 2; i++)
    gld16(&Kg[(size_t)(kvbeg + i * 32 + s_r) * 64 + s_sl * 8],
          &KVs[g][0][0][i * 2048 + ws * 512]);
#pragma unroll
  for (int i = 0; i < 2; i++)
    gld16(&Vtg[(size_t)(i * 32 + s_r) * N_ + kvbeg + s_sl * 8],
          &KVs[g][0][1][i * 2048 + ws * 512]);

  int cur = 0;
  for (int it = 0; it < 16; ++it) {
    __syncthreads();

    if (it + 1 < 16) {
      int kvn = kvbeg + (it + 1) * 64;
#pragma unroll
      for (int i = 0; i < 2; i++)
        gld16(&Kg[(size_t)(kvn + i * 32 + s_r) * 64 + s_sl * 8],
              &KVs[g][cur ^ 1][0][i * 2048 + ws * 512]);
#pragma unroll
      for (int i = 0; i < 2; i++)
        gld16(&Vtg[(size_t)(i * 32 + s_r) * N_ + kvn + s_sl * 8],
              &KVs[g][cur ^ 1][1][i * 2048 + ws * 512]);
    }

    const unsigned short* Kl = &KVs[g][cur][0][0];
    const unsigned short* Vl = &KVs[g][cur][1][0];

    u32 F[4][4];
#pragma unroll
    for (int t = 0; t < 2; t++) {
      f32x16 sa = minit;
      __builtin_amdgcn_s_setprio(1);
#pragma unroll
      for (int ds = 0; ds < 4; ds++) {
        bf16x8 a = *(const bf16x8*)&Kl[(t * 32 + l31) * 64 + ((ds * 16 + hi * 8) ^ swz)];
        sa = __builtin_amdgcn_mfma_f32_32x32x16_bf16(a, qf[ds], sa, 0, 0, 0);
      }
      __builtin_amdgcn_s_setprio(0);

      float p[16];
#pragma unroll
      for (int r = 0; r < 16; r++) p[r] = __builtin_amdgcn_exp2f(sa[r]);
      lrow += ((p[0] + p[1]) + (p[2] + p[3])) + ((p[4] + p[5]) + (p[6] + p[7]))
            + ((p[8] + p[9]) + (p[10] + p[11])) + ((p[12] + p[13]) + (p[14] + p[15]));

      u32 pk[8];
#pragma unroll
      for (int j = 0; j < 8; j++) pk[j] = pk2(p[2 * j], p[2 * j + 1]);
#if __has_builtin(__builtin_amdgcn_permlane32_swap)
      u32x2 r02 = __builtin_amdgcn_permlane32_swap(pk[0], pk[2], false, false);
      u32x2 r13 = __builtin_amdgcn_permlane32_swap(pk[1], pk[3], false, false);
      u32x2 r46 = __builtin_amdgcn_permlane32_swap(pk[4], pk[6], false, false);
      u32x2 r57 = __builtin_amdgcn_permlane32_swap(pk[5], pk[7], false, false);
      F[2 * t][0] = r02[0]; F[2 * t][2] = r02[1];
      F[2 * t][1] = r13[0]; F[2 * t][3] = r13[1];
      F[2 * t + 1][0] = r46[0]; F[2 * t + 1][2] = r46[1];
      F[2 * t + 1][1] = r57[0]; F[2 * t + 1][3] = r57[1];
#else
      u32 sw[8];
#pragma unroll
      for (int j = 0; j < 8; j++) sw[j] = (u32)__shfl_xor((int)pk[j], 32);
      F[2 * t][0] = hi ? sw[2] : pk[0];
      F[2 * t][1] = hi ? sw[3] : pk[1];
      F[2 * t][2] = hi ? pk[2] : sw[0];
      F[2 * t][3] = hi ? pk[3] : sw[1];
      F[2 * t + 1][0] = hi ? sw[6] : pk[4];
      F[2 * t + 1][1] = hi ? sw[7] : pk[5];
      F[2 * t + 1][2] = hi ? pk[6] : sw[4];
      F[2 * t + 1][3] = hi ? pk[7] : sw[5];
#endif
    }

    __builtin_amdgcn_s_setprio(1);
#pragma unroll
    for (int ks = 0; ks < 4; ks++) {
      u32x4 fv = {F[ks][0], F[ks][1], F[ks][2], F[ks][3]};
      bf16x8 a = __builtin_bit_cast(bf16x8, fv);
      bf16x8 b0 = *(const bf16x8*)&Vl[(0 * 32 + l31) * 64 + ((ks * 16 + hi * 8) ^ swz)];
      acc0 = __builtin_amdgcn_mfma_f32_32x32x16_bf16(a, b0, acc0, 0, 0, 0);
      bf16x8 b1 = *(const bf16x8*)&Vl[(1 * 32 + l31) * 64 + ((ks * 16 + hi * 8) ^ swz)];
      acc1 = __builtin_amdgcn_mfma_f32_32x32x16_bf16(a, b1, acc1, 0, 0, 0);
    }
    __builtin_amdgcn_s_setprio(0);
    cur ^= 1;
  }

  float rs = lrow + __shfl_xor(lrow, 32);
  if (lane < 32) Lf[g][ws * 32 + l31] = rs;
  __syncthreads();

  if (g == 0) {
#pragma unroll
    for (int r = 0; r < 16; r++) {
      int qr = (r & 3) + 8 * (r >> 2) + 4 * hi;
      scratch[(ws * 32 + qr) * 64 + l31]      = acc0[r];
      scratch[(ws * 32 + qr) * 64 + 32 + l31] = acc1[r];
    }
  }
  __syncthreads();
  if (g == 1) {
    const int b = bh >> 4, h = bh & 15;
#pragma unroll
    for (int r = 0; r < 16; r++) {
      int qr = (r & 3) + 8 * (r >> 2) + 4 * hi;
      float inv = 1.0f / (Lf[0][ws * 32 + qr] + Lf[1][ws * 32 + qr]);
      float o0 = scratch[(ws * 32 + qr) * 64 + l31]      + acc0[r];
      float o1 = scratch[(ws * 32 + qr) * 64 + 32 + l31] + acc1[r];
      int nq = q0 + ws * 32 + qr;
      size_t ob0 = (((size_t)b * N_ + nq) * H_ + h) * D_;
      ob[ob0 + l31]      = f2bf(o0 * inv);
      ob[ob0 + 32 + l31] = f2bf(o1 * inv);
    }
  }
}

extern "C" void kernel_launch(void* const* d_in, const int* in_sizes, int n_in,
                              void* d_out, int out_size, void* d_ws, size_t ws_size,
                              hipStream_t stream) {
  const float* x      = (const float*)d_in[0];
  const float* w_qkv  = (const float*)d_in[1];
  const float* w_proj = (const float*)d_in[2];
  const float* b_proj = (const float*)d_in[3];
  float* out = (float*)d_out;

  const size_t qsz = (size_t)B_ * H_ * N_ * D_;
  unsigned short* qb     = (unsigned short*)d_ws;
  unsigned short* kb     = qb + qsz;
  unsigned short* vtb    = kb + qsz;                      // V transposed [bh][d][n]
  unsigned short* xbf    = vtb + qsz;
  unsigned short* ob     = xbf;                           // alias: x dead after qkv
  unsigned short* wqkv_t = xbf + qsz;
  unsigned short* wproj_t= wqkv_t + (size_t)3072 * 1024;

  cvt_bf16_kernel<<<4096, 256, 0, stream>>>(x, xbf);
  transpose_cvt_kernel<<<dim3(3072 / 32, 1024 / 32), 256, 0, stream>>>(w_qkv, wqkv_t, 1024, 3072);
  transpose_cvt_kernel<<<dim3(1024 / 32, 1024 / 32), 256, 0, stream>>>(w_proj, wproj_t, 1024, 1024);

  gemm256_kernel<<<dim3(3072 / 256, 8192 / 256), 512, 0, stream>>>(
      xbf, wqkv_t, qb, kb, vtb, 8192, 1024, 3072);

  // grid: x = bh (64), y = q-tile (16) -> same-bh blocks consecutive mod-8
  flash_kernel<<<dim3(B_ * H_, N_ / 128), 512, 0, stream>>>(qb, kb, vtb, ob);

  gemmproj_kernel<<<dim3(1024 / 128, 8192 / 256), 512, 0, stream>>>(
      ob, wproj_t, b_proj, out, 8192, 1024, 1024);
}